// Round 18
// baseline (1209.397 us; speedup 1.0000x reference)
//
#include <hip/hip_runtime.h>
#include <hip/hip_bf16.h>
#include <math.h>

#define NT 8192        // tokens (B*S)
#define HD 2048        // hidden
#define ID 4096        // intermediate
#define NE 8           // experts
#define MAXSLOT 17408  // 16384 + padding headroom (multiple of 128)
#define MAXRB 136      // MAXSLOT/128

typedef __bf16 bf16x8 __attribute__((ext_vector_type(8)));
typedef float f32x4 __attribute__((ext_vector_type(4)));

__device__ __forceinline__ float bf2f(unsigned short u){
  union{unsigned u; float f;} v; v.u = ((unsigned)u) << 16; return v.f;
}

// global_load_lds, 16B, offset field ALWAYS 0 (non-zero imm offset is HW-unverified; R11 NaN)
#define GLDS0(g, l) __builtin_amdgcn_global_load_lds( \
    (const __attribute__((address_space(1))) void*)(g), \
    (__attribute__((address_space(3))) void*)(l), 16, 0, 0)

// ---------- fp32 -> bf16 convert (4-elem units) ----------
__global__ __launch_bounds__(256) void cvt_kernel(const float* __restrict__ in,
                                                  __hip_bfloat16* __restrict__ outp, int n4){
  int i = blockIdx.x * blockDim.x + threadIdx.x;
  int stride = gridDim.x * blockDim.x;
  for (; i < n4; i += stride){
    float4 v = reinterpret_cast<const float4*>(in)[i];
    union{ushort4 u; __hip_bfloat16 h[4];} o;
    o.h[0] = __float2bfloat16(v.x); o.h[1] = __float2bfloat16(v.y);
    o.h[2] = __float2bfloat16(v.z); o.h[3] = __float2bfloat16(v.w);
    reinterpret_cast<ushort4*>(outp)[i] = o.u;
  }
}

// ---------- router: fp64 logits, top-2, softmax weights ----------
__global__ __launch_bounds__(256) void router_kernel(
    const float* __restrict__ x, const float* __restrict__ gw,
    float* __restrict__ logits_out, int* __restrict__ tokExp,
    float* __restrict__ tokW, int* __restrict__ cnt)
{
  int wave = (blockIdx.x * blockDim.x + threadIdx.x) >> 6;
  int lane = threadIdx.x & 63;
  if (wave >= NT) return;
  const float* xr = x + (long)wave * HD;
  double acc[NE];
  #pragma unroll
  for (int e = 0; e < NE; e++) acc[e] = 0.0;
  for (int k = lane; k < HD; k += 64){
    double xv = (double)xr[k];
    #pragma unroll
    for (int e = 0; e < NE; e++) acc[e] += xv * (double)gw[e * HD + k];
  }
  #pragma unroll
  for (int e = 0; e < NE; e++){
    #pragma unroll
    for (int off = 32; off; off >>= 1) acc[e] += __shfl_down(acc[e], off, 64);
  }
  if (lane == 0){
    int e0 = 0; double v0 = acc[0];
    for (int e = 1; e < NE; e++) if (acc[e] > v0){ v0 = acc[e]; e0 = e; }
    int e1 = -1; double v1 = -1e300;
    for (int e = 0; e < NE; e++) if (e != e0 && acc[e] > v1){ v1 = acc[e]; e1 = e; }
    double ex = exp(v1 - v0);
    double s = 1.0 + ex;
    for (int e = 0; e < NE; e++) logits_out[wave * NE + e] = (float)acc[e];
    tokExp[wave * 2]     = e0; tokExp[wave * 2 + 1] = e1;
    tokW[wave * 2]       = (float)(1.0 / s);
    tokW[wave * 2 + 1]   = (float)(ex / s);
    atomicAdd(&cnt[e0], 1); atomicAdd(&cnt[e1], 1);
  }
}

// ---------- padded exclusive prefix over expert counts ----------
__global__ void offsets_kernel(const int* __restrict__ cnt, int* __restrict__ padOff){
  if (threadIdx.x == 0 && blockIdx.x == 0){
    int o = 0;
    for (int e = 0; e < NE; e++){ padOff[e] = o; o += ((cnt[e] + 127) >> 7) << 7; }
    padOff[NE] = o;
  }
}

// ---------- scatter: slotTok[slot] = token*2 + which (pair id), -1 for pads ----------
__global__ __launch_bounds__(256) void scatter_kernel(
    const int* __restrict__ tokExp, const int* __restrict__ padOff, int* cursor,
    int* __restrict__ slotTok)
{
  int t = blockIdx.x * blockDim.x + threadIdx.x;
  if (t >= NT) return;
  #pragma unroll
  for (int s = 0; s < 2; s++){
    int e = tokExp[t * 2 + s];
    int pos = atomicAdd(&cursor[e], 1);
    slotTok[padOff[e] + pos] = t * 2 + s;
  }
}

// ======== 128x128 grouped GEMM (R12 schedule) ========
// GATHER_A=1: A row = slotTok[slot]>>1 (token).  GATHER_A=0: A row = slot row.
// EPI=0: gelu(acc+bias) -> Yout[slot row] (fc).  EPI=1: atomic combine (proj):
//   out[tok*HD+col] += tokW[pair] * (acc+bias); pads skipped. Exactly 2 commutative
//   fp32 adds per output element -> bit-deterministic.
// FUSE_CVT: blocks >= GEMM_BLKS run grid-stride fp32->bf16 cvt (cvIn -> cvOut).
template<int GATHER_A, int EPI, int ND, int KD, int FUSE_CVT>
__global__ __launch_bounds__(256, 3) void moe_gemm_v12(
    const __hip_bfloat16* __restrict__ A,
    const __hip_bfloat16* __restrict__ W,   // bf16 [NE][ND][KD]
    const float* __restrict__ bias,
    const int* __restrict__ slotTok,
    const int* __restrict__ padOff,
    __hip_bfloat16* __restrict__ Yout,
    const float* __restrict__ tokWt,
    float* __restrict__ outF,
    const float* __restrict__ cvIn,
    __hip_bfloat16* __restrict__ cvOut)
{
  __shared__ __align__(16) __hip_bfloat16 lds[3 * 8192];  // buf: A[0..4095] B[4096..8191]
  constexpr int NCB = ND / 128;
  constexpr int GEMM_BLKS = NCB * MAXRB;
  int cb, rb;
  if (FUSE_CVT){
    const int bid = blockIdx.x;
    if (bid >= GEMM_BLKS){
      const int n4 = NE * ID * HD / 4;
      int i = (bid - GEMM_BLKS) * 256 + (int)threadIdx.x;
      const int stride = 4096 * 256;
      for (; i < n4; i += stride){
        float4 v = reinterpret_cast<const float4*>(cvIn)[i];
        union{ushort4 u; __hip_bfloat16 h[4];} o;
        o.h[0] = __float2bfloat16(v.x); o.h[1] = __float2bfloat16(v.y);
        o.h[2] = __float2bfloat16(v.z); o.h[3] = __float2bfloat16(v.w);
        reinterpret_cast<ushort4*>(cvOut)[i] = o.u;
      }
      return;
    }
    cb = bid % NCB; rb = bid / NCB;
  } else {
    cb = blockIdx.x; rb = blockIdx.y;
  }
  if (rb * 128 >= padOff[NE]) return;
  int e = 0;
  #pragma unroll
  for (int i = 1; i < NE; i++) if (rb * 128 >= padOff[i]) e = i;

  const int tid  = threadIdx.x;
  const int lane = tid & 63;
  const int w    = tid >> 6;           // 0..3
  const int wr   = w >> 1, wc = w & 1;

  const int r16s = lane >> 2;
  const int cgs  = (lane & 3) ^ ((r16s >> 1) & 3);   // inverse swizzle on global k-chunk
  long aRow0, aRow1;
  {
    int g0 = rb * 128 + 32 * w + r16s, g1 = g0 + 16;
    if (GATHER_A){
      int t0 = slotTok[g0]; aRow0 = t0 < 0 ? 0 : (t0 >> 1);
      int t1 = slotTok[g1]; aRow1 = t1 < 0 ? 0 : (t1 >> 1);
    } else { aRow0 = g0; aRow1 = g1; }
  }
  const __hip_bfloat16* sA0 = A + aRow0 * (long)KD + cgs * 8;
  const __hip_bfloat16* sA1 = A + aRow1 * (long)KD + cgs * 8;
  const long bRow0 = (long)cb * 128 + 32 * w + r16s;
  const __hip_bfloat16* sB0 = W + (long)e * ND * KD + bRow0 * KD + cgs * 8;
  const __hip_bfloat16* sB1 = sB0 + 16 * (long)KD;

  __hip_bfloat16* dst0 = &lds[0 * 8192 + 2 * w * 512];
  __hip_bfloat16* dst1 = &lds[1 * 8192 + 2 * w * 512];
  __hip_bfloat16* dst2 = &lds[2 * 8192 + 2 * w * 512];

  const int r16f  = lane & 15;
  const int laneF = r16f * 32 + (((lane >> 4) ^ ((r16f >> 1) & 3))) * 8;
  const int adrA  = wr * 2048 + laneF;
  const int adrB  = 4096 + wc * 2048 + laneF;

  f32x4 acc[4][4] = {};

  constexpr int NKS = KD / 32;

#define STGADV(DP) do{ \
    GLDS0(sA0, (DP)); GLDS0(sA1, (DP) + 512); \
    GLDS0(sB0, (DP) + 4096); GLDS0(sB1, (DP) + 4096 + 512); \
    sA0 += 32; sA1 += 32; sB0 += 32; sB1 += 32; \
    asm volatile("" : "+v"(sA0), "+v"(sA1), "+v"(sB0), "+v"(sB1)); \
  }while(0)

#define RD_A(BUFC, M) (*reinterpret_cast<const bf16x8*>(&lds[(BUFC)*8192 + (M)*512 + adrA]))
#define RD_B(BUFC, N) (*reinterpret_cast<const bf16x8*>(&lds[(BUFC)*8192 + (N)*512 + adrB]))

#define BODY(K, BUFC, DP_STG) do{ \
    const int tt = t + (K); \
    if (tt < NKS){ \
      const bool dost = (tt + 2 < NKS); \
      if (dost){ STGADV(DP_STG); } \
      bf16x8 a0 = RD_A(BUFC,0), a1 = RD_A(BUFC,1), a2 = RD_A(BUFC,2), a3 = RD_A(BUFC,3); \
      bf16x8 b0 = RD_B(BUFC,0), b1 = RD_B(BUFC,1), b2 = RD_B(BUFC,2), b3 = RD_B(BUFC,3); \
      __builtin_amdgcn_s_setprio(1); \
      acc[0][0] = __builtin_amdgcn_mfma_f32_16x16x32_bf16(a0, b0, acc[0][0],0,0,0); \
      acc[1][0] = __builtin_amdgcn_mfma_f32_16x16x32_bf16(a1, b0, acc[1][0],0,0,0); \
      acc[2][0] = __builtin_amdgcn_mfma_f32_16x16x32_bf16(a2, b0, acc[2][0],0,0,0); \
      acc[3][0] = __builtin_amdgcn_mfma_f32_16x16x32_bf16(a3, b0, acc[3][0],0,0,0); \
      acc[0][1] = __builtin_amdgcn_mfma_f32_16x16x32_bf16(a0, b1, acc[0][1],0,0,0); \
      acc[1][1] = __builtin_amdgcn_mfma_f32_16x16x32_bf16(a1, b1, acc[1][1],0,0,0); \
      acc[2][1] = __builtin_amdgcn_mfma_f32_16x16x32_bf16(a2, b1, acc[2][1],0,0,0); \
      acc[3][1] = __builtin_amdgcn_mfma_f32_16x16x32_bf16(a3, b1, acc[3][1],0,0,0); \
      acc[0][2] = __builtin_amdgcn_mfma_f32_16x16x32_bf16(a0, b2, acc[0][2],0,0,0); \
      acc[1][2] = __builtin_amdgcn_mfma_f32_16x16x32_bf16(a1, b2, acc[1][2],0,0,0); \
      acc[2][2] = __builtin_amdgcn_mfma_f32_16x16x32_bf16(a2, b2, acc[2][2],0,0,0); \
      acc[3][2] = __builtin_amdgcn_mfma_f32_16x16x32_bf16(a3, b2, acc[3][2],0,0,0); \
      acc[0][3] = __builtin_amdgcn_mfma_f32_16x16x32_bf16(a0, b3, acc[0][3],0,0,0); \
      acc[1][3] = __builtin_amdgcn_mfma_f32_16x16x32_bf16(a1, b3, acc[1][3],0,0,0); \
      acc[2][3] = __builtin_amdgcn_mfma_f32_16x16x32_bf16(a2, b3, acc[2][3],0,0,0); \
      acc[3][3] = __builtin_amdgcn_mfma_f32_16x16x32_bf16(a3, b3, acc[3][3],0,0,0); \
      __builtin_amdgcn_s_setprio(0); \
      if (dost) asm volatile("s_waitcnt vmcnt(4)" ::: "memory"); \
      else      asm volatile("s_waitcnt vmcnt(0)" ::: "memory"); \
      __builtin_amdgcn_s_barrier(); \
    } \
  }while(0)

  STGADV(dst0);
  STGADV(dst1);
  asm volatile("s_waitcnt vmcnt(4)" ::: "memory");
  __builtin_amdgcn_s_barrier();

  for (int t = 0; t < NKS; t += 3){
    BODY(0, 0, dst2);
    BODY(1, 1, dst0);
    BODY(2, 2, dst1);
  }

  const int col0 = cb * 128 + wc * 64 + (lane & 15);
  const int row0 = rb * 128 + wr * 64 + (lane >> 4) * 4;
  float bb[4];
  #pragma unroll
  for (int n = 0; n < 4; n++) bb[n] = bias[(long)e * ND + col0 + n * 16];

  if (EPI == 0){
    // fc: gelu -> bf16 Yout[slot row]
    #pragma unroll
    for (int m = 0; m < 4; m++){
      const long rbase = (long)(row0 + m * 16);
      #pragma unroll
      for (int r = 0; r < 4; r++){
        #pragma unroll
        for (int n = 0; n < 4; n++){
          float v = acc[m][n][r] + bb[n];
          // tanh-form GELU (max dev from exact ~3e-3; NaN-free for all finite v)
          float u = 0.7978845608f * (v + 0.044715f * v * v * v);
          float t2 = 1.0f - 2.0f / (__expf(2.0f * u) + 1.0f);
          v = 0.5f * v * (1.0f + t2);
          Yout[rbase * ND + (long)r * ND + col0 + n * 16] = __float2bfloat16(v);
        }
      }
    }
  } else {
    // proj: atomic combine into fp32 out; pads skipped; 2 commutative adds/elem
    #pragma unroll
    for (int m = 0; m < 4; m++){
      #pragma unroll
      for (int r = 0; r < 4; r++){
        const int pr = slotTok[row0 + m * 16 + r];
        if (pr >= 0){
          const long tok = pr >> 1;
          const float wgt = tokWt[pr];
          float* dst = outF + tok * HD + col0;
          #pragma unroll
          for (int n = 0; n < 4; n++){
            atomicAdd(dst + n * 16, wgt * (acc[m][n][r] + bb[n]));
          }
        }
      }
    }
  }
#undef STGADV
#undef RD_A
#undef RD_B
#undef BODY
}

extern "C" void kernel_launch(void* const* d_in, const int* in_sizes, int n_in,
                              void* d_out, int out_size, void* d_ws, size_t ws_size,
                              hipStream_t stream)
{
  (void)in_sizes; (void)n_in; (void)out_size;
  const float* x     = (const float*)d_in[0];
  const float* gw    = (const float*)d_in[1];
  const float* wfc   = (const float*)d_in[2];
  const float* bfc   = (const float*)d_in[3];
  const float* wproj = (const float*)d_in[4];
  const float* bproj = (const float*)d_in[5];
  float* outp   = (float*)d_out;
  float* logits = outp + (size_t)NT * HD;

  char* ws = (char*)d_ws;
  size_t off = 0;
  auto alloc = [&](size_t b){ void* p = ws + off; off += (b + 255) & ~(size_t)255; return p; };

  __hip_bfloat16* xb = (__hip_bfloat16*)alloc((size_t)NT * HD * 2);       // 33.5 MB
  __hip_bfloat16* hb = (__hip_bfloat16*)alloc((size_t)MAXSLOT * ID * 2);  // 142.6 MB
  int*   slotTok = (int*)alloc(MAXSLOT * 4);
  int*   tokExp  = (int*)alloc(NT * 2 * 4);
  float* tokW    = (float*)alloc(NT * 2 * 4);
  int*   meta    = (int*)alloc(256);
  int* cnt = meta; int* cursor = meta + 8; int* padOff = meta + 16;

  const size_t WB1 = (size_t)NE * ID * HD * 2;   // one weight tensor, bf16 (134.2 MB)
  const bool dual = (off + 2 * WB1) <= ws_size;
  __hip_bfloat16* wBa = (__hip_bfloat16*)(ws + off);
  __hip_bfloat16* wBb = dual ? (__hip_bfloat16*)(ws + off + WB1) : wBa;

  hipMemsetAsync(meta, 0, 256, stream);
  hipMemsetAsync(slotTok, 0xFF, MAXSLOT * 4, stream);
  hipMemsetAsync(outp, 0, (size_t)NT * HD * 4, stream);   // atomic-combine target

  cvt_kernel<<<2048, 256, 0, stream>>>(x, xb, NT * HD / 4);
  router_kernel<<<NT / 4, 256, 0, stream>>>(x, gw, logits, tokExp, tokW, cnt);
  offsets_kernel<<<1, 64, 0, stream>>>(cnt, padOff);
  scatter_kernel<<<NT / 256, 256, 0, stream>>>(tokExp, padOff, cursor, slotTok);

  cvt_kernel<<<4096, 256, 0, stream>>>(wfc, wBa, NE * ID * HD / 4);

  if (dual){
    moe_gemm_v12<1, 0, ID, HD, 1><<<(ID / 128) * MAXRB + 4096, 256, 0, stream>>>(
        xb, wBa, bfc, slotTok, padOff, hb, nullptr, nullptr, wproj, wBb);
    moe_gemm_v12<0, 1, HD, ID, 0><<<dim3(HD / 128, MAXRB), 256, 0, stream>>>(
        hb, wBb, bproj, slotTok, padOff, nullptr, tokW, outp, nullptr, nullptr);
  } else {
    moe_gemm_v12<1, 0, ID, HD, 0><<<dim3(ID / 128, MAXRB), 256, 0, stream>>>(
        xb, wBa, bfc, slotTok, padOff, hb, nullptr, nullptr, nullptr, nullptr);
    cvt_kernel<<<4096, 256, 0, stream>>>(wproj, wBb, NE * HD * ID / 4);
    moe_gemm_v12<0, 1, HD, ID, 0><<<dim3(HD / 128, MAXRB), 256, 0, stream>>>(
        hb, wBb, bproj, slotTok, padOff, nullptr, tokW, outp, nullptr, nullptr);
  }
}

// Round 19
// 1189.797 us; speedup vs baseline: 1.0165x; 1.0165x over previous
//
#include <hip/hip_runtime.h>
#include <hip/hip_bf16.h>
#include <math.h>

#define NT 8192        // tokens (B*S)
#define HD 2048        // hidden
#define ID 4096        // intermediate
#define NE 8           // experts
#define MAXSLOT 17408  // 16384 + padding headroom (multiple of 128)
#define MAXRB 136      // MAXSLOT/128

typedef __bf16 bf16x8 __attribute__((ext_vector_type(8)));
typedef float f32x4 __attribute__((ext_vector_type(4)));

__device__ __forceinline__ float bf2f(unsigned short u){
  union{unsigned u; float f;} v; v.u = ((unsigned)u) << 16; return v.f;
}

// global_load_lds, 16B, offset field ALWAYS 0 (non-zero imm offset is HW-unverified; R11 NaN)
#define GLDS0(g, l) __builtin_amdgcn_global_load_lds( \
    (const __attribute__((address_space(1))) void*)(g), \
    (__attribute__((address_space(3))) void*)(l), 16, 0, 0)

// ---------- fp32 -> bf16 convert (4-elem units; proven ~3.5 TB/s) ----------
__global__ __launch_bounds__(256) void cvt_kernel(const float* __restrict__ in,
                                                  __hip_bfloat16* __restrict__ outp, int n4){
  int i = blockIdx.x * blockDim.x + threadIdx.x;
  int stride = gridDim.x * blockDim.x;
  for (; i < n4; i += stride){
    float4 v = reinterpret_cast<const float4*>(in)[i];
    union{ushort4 u; __hip_bfloat16 h[4];} o;
    o.h[0] = __float2bfloat16(v.x); o.h[1] = __float2bfloat16(v.y);
    o.h[2] = __float2bfloat16(v.z); o.h[3] = __float2bfloat16(v.w);
    reinterpret_cast<ushort4*>(outp)[i] = o.u;
  }
}

// ---------- router: fp64 logits, top-2, softmax weights ----------
__global__ __launch_bounds__(256) void router_kernel(
    const float* __restrict__ x, const float* __restrict__ gw,
    float* __restrict__ logits_out, int* __restrict__ tokExp,
    float* __restrict__ tokW, int* __restrict__ cnt)
{
  int wave = (blockIdx.x * blockDim.x + threadIdx.x) >> 6;
  int lane = threadIdx.x & 63;
  if (wave >= NT) return;
  const float* xr = x + (long)wave * HD;
  double acc[NE];
  #pragma unroll
  for (int e = 0; e < NE; e++) acc[e] = 0.0;
  for (int k = lane; k < HD; k += 64){
    double xv = (double)xr[k];
    #pragma unroll
    for (int e = 0; e < NE; e++) acc[e] += xv * (double)gw[e * HD + k];
  }
  #pragma unroll
  for (int e = 0; e < NE; e++){
    #pragma unroll
    for (int off = 32; off; off >>= 1) acc[e] += __shfl_down(acc[e], off, 64);
  }
  if (lane == 0){
    int e0 = 0; double v0 = acc[0];
    for (int e = 1; e < NE; e++) if (acc[e] > v0){ v0 = acc[e]; e0 = e; }
    int e1 = -1; double v1 = -1e300;
    for (int e = 0; e < NE; e++) if (e != e0 && acc[e] > v1){ v1 = acc[e]; e1 = e; }
    double ex = exp(v1 - v0);
    double s = 1.0 + ex;
    for (int e = 0; e < NE; e++) logits_out[wave * NE + e] = (float)acc[e];
    tokExp[wave * 2]     = e0; tokExp[wave * 2 + 1] = e1;
    tokW[wave * 2]       = (float)(1.0 / s);
    tokW[wave * 2 + 1]   = (float)(ex / s);
    atomicAdd(&cnt[e0], 1); atomicAdd(&cnt[e1], 1);
  }
}

// ---------- padded exclusive prefix over expert counts ----------
__global__ void offsets_kernel(const int* __restrict__ cnt, int* __restrict__ padOff){
  if (threadIdx.x == 0 && blockIdx.x == 0){
    int o = 0;
    for (int e = 0; e < NE; e++){ padOff[e] = o; o += ((cnt[e] + 127) >> 7) << 7; }
    padOff[NE] = o;
  }
}

// ---------- scatter tokens into padded per-expert segments ----------
__global__ __launch_bounds__(256) void scatter_kernel(
    const int* __restrict__ tokExp, const float* __restrict__ tokW,
    const int* __restrict__ padOff, int* cursor,
    int* __restrict__ slotTok, int* __restrict__ tokSlot)
{
  int t = blockIdx.x * blockDim.x + threadIdx.x;
  if (t >= NT) return;
  #pragma unroll
  for (int s = 0; s < 2; s++){
    int e = tokExp[t * 2 + s];
    int pos = atomicAdd(&cursor[e], 1);
    int slot = padOff[e] + pos;
    slotTok[slot] = t;
    tokSlot[t * 2 + s] = slot;
  }
}

// ======== 128x128 grouped GEMM (R12-verified schedule) ========
// FUSE_CVT: blocks >= GEMM_BLKS run a grid-stride fp32->bf16 cvt of (cvIn -> cvOut)
// instead of GEMM work — hides the NEXT GEMM's weight conversion in this dispatch's
// BW headroom (GEMM runs at ~1.6 TB/s of 8). No inter-block deps; order-independent.
template<int GATHER_A, int EPI, int ND, int KD, int FUSE_CVT>
__global__ __launch_bounds__(256, 3) void moe_gemm_v12(
    const __hip_bfloat16* __restrict__ A,
    const __hip_bfloat16* __restrict__ W,   // bf16 [NE][ND][KD]
    const float* __restrict__ bias,
    const int* __restrict__ slotTok,
    const int* __restrict__ padOff,
    __hip_bfloat16* __restrict__ Yout,
    const float* __restrict__ cvIn,
    __hip_bfloat16* __restrict__ cvOut)
{
  __shared__ __align__(16) __hip_bfloat16 lds[3 * 8192];  // buf: A[0..4095] B[4096..8191]
  constexpr int NCB = ND / 128;
  constexpr int GEMM_BLKS = NCB * MAXRB;
  int cb, rb;
  if (FUSE_CVT){
    const int bid = blockIdx.x;
    if (bid >= GEMM_BLKS){
      // appended cvt blocks: convert next GEMM's weights (16 iters/thread, exact)
      const int n4 = NE * ID * HD / 4;
      int i = (bid - GEMM_BLKS) * 256 + (int)threadIdx.x;
      const int stride = 4096 * 256;
      for (; i < n4; i += stride){
        float4 v = reinterpret_cast<const float4*>(cvIn)[i];
        union{ushort4 u; __hip_bfloat16 h[4];} o;
        o.h[0] = __float2bfloat16(v.x); o.h[1] = __float2bfloat16(v.y);
        o.h[2] = __float2bfloat16(v.z); o.h[3] = __float2bfloat16(v.w);
        reinterpret_cast<ushort4*>(cvOut)[i] = o.u;
      }
      return;
    }
    cb = bid % NCB; rb = bid / NCB;
  } else {
    cb = blockIdx.x; rb = blockIdx.y;
  }
  if (rb * 128 >= padOff[NE]) return;
  int e = 0;
  #pragma unroll
  for (int i = 1; i < NE; i++) if (rb * 128 >= padOff[i]) e = i;

  const int tid  = threadIdx.x;
  const int lane = tid & 63;
  const int w    = tid >> 6;           // 0..3
  const int wr   = w >> 1, wc = w & 1;

  const int r16s = lane >> 2;
  const int cgs  = (lane & 3) ^ ((r16s >> 1) & 3);   // inverse swizzle on global k-chunk
  long aRow0, aRow1;
  {
    int g0 = rb * 128 + 32 * w + r16s, g1 = g0 + 16;
    if (GATHER_A){
      int t0 = slotTok[g0]; if (t0 < 0) t0 = 0;
      int t1 = slotTok[g1]; if (t1 < 0) t1 = 0;
      aRow0 = t0; aRow1 = t1;
    } else { aRow0 = g0; aRow1 = g1; }
  }
  const __hip_bfloat16* sA0 = A + aRow0 * (long)KD + cgs * 8;
  const __hip_bfloat16* sA1 = A + aRow1 * (long)KD + cgs * 8;
  const long bRow0 = (long)cb * 128 + 32 * w + r16s;
  const __hip_bfloat16* sB0 = W + (long)e * ND * KD + bRow0 * KD + cgs * 8;
  const __hip_bfloat16* sB1 = sB0 + 16 * (long)KD;

  __hip_bfloat16* dst0 = &lds[0 * 8192 + 2 * w * 512];
  __hip_bfloat16* dst1 = &lds[1 * 8192 + 2 * w * 512];
  __hip_bfloat16* dst2 = &lds[2 * 8192 + 2 * w * 512];

  const int r16f  = lane & 15;
  const int laneF = r16f * 32 + (((lane >> 4) ^ ((r16f >> 1) & 3))) * 8;
  const int adrA  = wr * 2048 + laneF;
  const int adrB  = 4096 + wc * 2048 + laneF;

  f32x4 acc[4][4] = {};

  constexpr int NKS = KD / 32;

#define STGADV(DP) do{ \
    GLDS0(sA0, (DP)); GLDS0(sA1, (DP) + 512); \
    GLDS0(sB0, (DP) + 4096); GLDS0(sB1, (DP) + 4096 + 512); \
    sA0 += 32; sA1 += 32; sB0 += 32; sB1 += 32; \
    asm volatile("" : "+v"(sA0), "+v"(sA1), "+v"(sB0), "+v"(sB1)); \
  }while(0)

#define RD_A(BUFC, M) (*reinterpret_cast<const bf16x8*>(&lds[(BUFC)*8192 + (M)*512 + adrA]))
#define RD_B(BUFC, N) (*reinterpret_cast<const bf16x8*>(&lds[(BUFC)*8192 + (N)*512 + adrB]))

#define BODY(K, BUFC, DP_STG) do{ \
    const int tt = t + (K); \
    if (tt < NKS){ \
      const bool dost = (tt + 2 < NKS); \
      if (dost){ STGADV(DP_STG); } \
      bf16x8 a0 = RD_A(BUFC,0), a1 = RD_A(BUFC,1), a2 = RD_A(BUFC,2), a3 = RD_A(BUFC,3); \
      bf16x8 b0 = RD_B(BUFC,0), b1 = RD_B(BUFC,1), b2 = RD_B(BUFC,2), b3 = RD_B(BUFC,3); \
      __builtin_amdgcn_s_setprio(1); \
      acc[0][0] = __builtin_amdgcn_mfma_f32_16x16x32_bf16(a0, b0, acc[0][0],0,0,0); \
      acc[1][0] = __builtin_amdgcn_mfma_f32_16x16x32_bf16(a1, b0, acc[1][0],0,0,0); \
      acc[2][0] = __builtin_amdgcn_mfma_f32_16x16x32_bf16(a2, b0, acc[2][0],0,0,0); \
      acc[3][0] = __builtin_amdgcn_mfma_f32_16x16x32_bf16(a3, b0, acc[3][0],0,0,0); \
      acc[0][1] = __builtin_amdgcn_mfma_f32_16x16x32_bf16(a0, b1, acc[0][1],0,0,0); \
      acc[1][1] = __builtin_amdgcn_mfma_f32_16x16x32_bf16(a1, b1, acc[1][1],0,0,0); \
      acc[2][1] = __builtin_amdgcn_mfma_f32_16x16x32_bf16(a2, b1, acc[2][1],0,0,0); \
      acc[3][1] = __builtin_amdgcn_mfma_f32_16x16x32_bf16(a3, b1, acc[3][1],0,0,0); \
      acc[0][2] = __builtin_amdgcn_mfma_f32_16x16x32_bf16(a0, b2, acc[0][2],0,0,0); \
      acc[1][2] = __builtin_amdgcn_mfma_f32_16x16x32_bf16(a1, b2, acc[1][2],0,0,0); \
      acc[2][2] = __builtin_amdgcn_mfma_f32_16x16x32_bf16(a2, b2, acc[2][2],0,0,0); \
      acc[3][2] = __builtin_amdgcn_mfma_f32_16x16x32_bf16(a3, b2, acc[3][2],0,0,0); \
      acc[0][3] = __builtin_amdgcn_mfma_f32_16x16x32_bf16(a0, b3, acc[0][3],0,0,0); \
      acc[1][3] = __builtin_amdgcn_mfma_f32_16x16x32_bf16(a1, b3, acc[1][3],0,0,0); \
      acc[2][3] = __builtin_amdgcn_mfma_f32_16x16x32_bf16(a2, b3, acc[2][3],0,0,0); \
      acc[3][3] = __builtin_amdgcn_mfma_f32_16x16x32_bf16(a3, b3, acc[3][3],0,0,0); \
      __builtin_amdgcn_s_setprio(0); \
      if (dost) asm volatile("s_waitcnt vmcnt(4)" ::: "memory"); \
      else      asm volatile("s_waitcnt vmcnt(0)" ::: "memory"); \
      __builtin_amdgcn_s_barrier(); \
    } \
  }while(0)

  STGADV(dst0);
  STGADV(dst1);
  asm volatile("s_waitcnt vmcnt(4)" ::: "memory");
  __builtin_amdgcn_s_barrier();

  for (int t = 0; t < NKS; t += 3){
    BODY(0, 0, dst2);
    BODY(1, 1, dst0);
    BODY(2, 2, dst1);
  }

  const int col0 = cb * 128 + wc * 64 + (lane & 15);
  const int row0 = rb * 128 + wr * 64 + (lane >> 4) * 4;
  #pragma unroll
  for (int n = 0; n < 4; n++){
    const int col = col0 + n * 16;
    const float bb = bias[(long)e * ND + col];
    #pragma unroll
    for (int m = 0; m < 4; m++){
      const long rbase = (long)(row0 + m * 16);
      #pragma unroll
      for (int r = 0; r < 4; r++){
        float v = acc[m][n][r] + bb;
        if (EPI == 0){
          // tanh-form GELU (max dev from exact ~3e-3; NaN-free for all finite v)
          float u = 0.7978845608f * (v + 0.044715f * v * v * v);
          float t2 = 1.0f - 2.0f / (__expf(2.0f * u) + 1.0f);
          v = 0.5f * v * (1.0f + t2);
        }
        Yout[(rbase + r) * ND + col] = __float2bfloat16(v);
      }
    }
  }
#undef STGADV
#undef RD_A
#undef RD_B
#undef BODY
}

// ---------- combine: out[t] = w0*y[slot0] + w1*y[slot1] ----------
__global__ __launch_bounds__(256) void combine_kernel(
    const __hip_bfloat16* __restrict__ yb,
    const int* __restrict__ tokSlot, const float* __restrict__ tokW,
    float* __restrict__ outp)
{
  const int t  = blockIdx.x;
  const int c0 = threadIdx.x * 8;
  const int s0 = tokSlot[t * 2], s1 = tokSlot[t * 2 + 1];
  const float w0 = tokW[t * 2], w1 = tokW[t * 2 + 1];
  const ushort4* p0 = reinterpret_cast<const ushort4*>(yb + (long)s0 * HD + c0);
  const ushort4* p1 = reinterpret_cast<const ushort4*>(yb + (long)s1 * HD + c0);
  float4 o[2];
  #pragma unroll
  for (int h = 0; h < 2; h++){
    ushort4 a = p0[h], b = p1[h];
    o[h].x = w0 * bf2f(a.x) + w1 * bf2f(b.x);
    o[h].y = w0 * bf2f(a.y) + w1 * bf2f(b.y);
    o[h].z = w0 * bf2f(a.z) + w1 * bf2f(b.z);
    o[h].w = w0 * bf2f(a.w) + w1 * bf2f(b.w);
  }
  float4* po = reinterpret_cast<float4*>(outp + (long)t * HD + c0);
  po[0] = o[0]; po[1] = o[1];
}

extern "C" void kernel_launch(void* const* d_in, const int* in_sizes, int n_in,
                              void* d_out, int out_size, void* d_ws, size_t ws_size,
                              hipStream_t stream)
{
  (void)in_sizes; (void)n_in; (void)out_size;
  const float* x     = (const float*)d_in[0];
  const float* gw    = (const float*)d_in[1];
  const float* wfc   = (const float*)d_in[2];
  const float* bfc   = (const float*)d_in[3];
  const float* wproj = (const float*)d_in[4];
  const float* bproj = (const float*)d_in[5];
  float* outp   = (float*)d_out;
  float* logits = outp + (size_t)NT * HD;

  char* ws = (char*)d_ws;
  size_t off = 0;
  auto alloc = [&](size_t b){ void* p = ws + off; off += (b + 255) & ~(size_t)255; return p; };

  // xb (fc input) and yb (proj output) have disjoint lifetimes -> share region
  char* shared0 = (char*)alloc((size_t)MAXSLOT * HD * 2);               // 71 MB
  __hip_bfloat16* xb = (__hip_bfloat16*)shared0;
  __hip_bfloat16* yb = (__hip_bfloat16*)shared0;
  __hip_bfloat16* hb = (__hip_bfloat16*)alloc((size_t)MAXSLOT * ID * 2); // 142.6 MB
  int*   slotTok = (int*)alloc(MAXSLOT * 4);
  int*   tokExp  = (int*)alloc(NT * 2 * 4);
  float* tokW    = (float*)alloc(NT * 2 * 4);
  int*   tokSlot = (int*)alloc(NT * 2 * 4);
  int*   meta    = (int*)alloc(256);
  int* cnt = meta; int* cursor = meta + 8; int* padOff = meta + 16;

  const size_t WB1 = (size_t)NE * ID * HD * 2;   // one weight tensor, bf16 (134.2 MB)
  const bool dual = (off + 2 * WB1) <= ws_size;
  __hip_bfloat16* wBa = (__hip_bfloat16*)(ws + off);
  __hip_bfloat16* wBb = dual ? (__hip_bfloat16*)(ws + off + WB1) : wBa;

  hipMemsetAsync(meta, 0, 256, stream);
  hipMemsetAsync(slotTok, 0xFF, MAXSLOT * 4, stream);

  cvt_kernel<<<2048, 256, 0, stream>>>(x, xb, NT * HD / 4);
  router_kernel<<<NT / 4, 256, 0, stream>>>(x, gw, logits, tokExp, tokW, cnt);
  offsets_kernel<<<1, 64, 0, stream>>>(cnt, padOff);
  scatter_kernel<<<NT / 256, 256, 0, stream>>>(tokExp, tokW, padOff, cursor, slotTok, tokSlot);

  cvt_kernel<<<4096, 256, 0, stream>>>(wfc, wBa, NE * ID * HD / 4);

  if (dual){
    // fc GEMM with appended wproj-cvt blocks (cvt hidden in GEMM BW headroom)
    moe_gemm_v12<1, 0, ID, HD, 1><<<(ID / 128) * MAXRB + 4096, 256, 0, stream>>>(
        xb, wBa, bfc, slotTok, padOff, hb, wproj, wBb);
    moe_gemm_v12<0, 1, HD, ID, 0><<<dim3(HD / 128, MAXRB), 256, 0, stream>>>(
        hb, wBb, bproj, slotTok, padOff, yb, nullptr, nullptr);
  } else {
    moe_gemm_v12<1, 0, ID, HD, 0><<<dim3(ID / 128, MAXRB), 256, 0, stream>>>(
        xb, wBa, bfc, slotTok, padOff, hb, nullptr, nullptr);
    cvt_kernel<<<4096, 256, 0, stream>>>(wproj, wBb, NE * HD * ID / 4);
    moe_gemm_v12<0, 1, HD, ID, 0><<<dim3(HD / 128, MAXRB), 256, 0, stream>>>(
        hb, wBb, bproj, slotTok, padOff, yb, nullptr, nullptr);
  }

  combine_kernel<<<NT, 256, 0, stream>>>(yb, tokSlot, tokW, outp);
}